// Round 12
// baseline (329.014 us; speedup 1.0000x reference)
//
#include <hip/hip_runtime.h>

#define BB 16
#define CC 256
#define NN 1024

typedef _Float16 f16;
typedef __attribute__((ext_vector_type(8))) _Float16 half8;   // MFMA A/B frag (4 VGPRs)
typedef __attribute__((ext_vector_type(4))) float f32x4;      // MFMA C/D frag

__device__ __forceinline__ half8 ldg8(const f16* p) {
  return *reinterpret_cast<const half8*>(p);
}

// ---------------- weight pack: W fp32 [ci][co] -> frag-packed f16 wp[(ct*8+kc)*512 + lane*8] ----
struct WP5 {
  const float* s[5];
  f16* d[5];
};

__global__ void __launch_bounds__(256) k_packW(WP5 p) {
  __shared__ float ws[256][17];
  int m = blockIdx.y, ct = blockIdx.x;
  const float* W = p.s[m];
  f16* wp = p.d[m];
  int tid = threadIdx.x;
  int col = tid & 15, cig = tid >> 4;
#pragma unroll
  for (int pg = 0; pg < 16; ++pg) {
    int ci = pg * 16 + cig;
    ws[ci][col] = W[(size_t)ci * 256 + ct * 16 + col];
  }
  __syncthreads();
  int lane = tid & 63, wave = tid >> 6;
  int row16 = lane & 15, quad = lane >> 4;
#pragma unroll
  for (int kk = 0; kk < 2; ++kk) {
    int kc = wave * 2 + kk;
    half8 o;
#pragma unroll
    for (int j = 0; j < 8; ++j) o[j] = (f16)ws[kc * 32 + quad * 8 + j][row16];
    *reinterpret_cast<half8*>(wp + ((size_t)ct * 8 + kc) * 512 + lane * 8) = o;
  }
}

// ---------------- QKV: x fp32 [bg][c][n] -> frag-packed q,k,vT (unchanged from R11) ----------------
struct QkvSmem {
  union {
    struct { f16 hi[32][264]; f16 lo[32][264]; } ts;
    f16 ex[2][16][264];
    f16 exv[256][40];
  };
};

__global__ void __launch_bounds__(256) k_qkv(const float* __restrict__ x,
    const f16* __restrict__ wqp, const f16* __restrict__ wkp, const f16* __restrict__ wvp,
    const float* __restrict__ bq, const float* __restrict__ bk, const float* __restrict__ bv,
    f16* __restrict__ qp, f16* __restrict__ kp, f16* __restrict__ vp, int b_base) {
  __shared__ QkvSmem sm;
  int z = blockIdx.z;
  const f16* WT     = (z == 0) ? wqp : (z == 1) ? wkp : wvp;
  const float* bias = (z == 0) ? bq  : (z == 1) ? bk  : bv;
  int bl = blockIdx.x, bg = b_base + bl, n0 = blockIdx.y * 32;
  int tid = threadIdx.x, wave = tid >> 6, lane = tid & 63;
  int row16 = lane & 15, quad = lane >> 4;
  int g = wave >> 1, h = wave & 1;

#pragma unroll
  for (int e = tid; e < 2048; e += 256) {
    int c = e >> 3, n4 = (e & 7) << 2;
    float4 u = *reinterpret_cast<const float4*>(x + (size_t)(bg * CC + c) * NN + n0 + n4);
    float uv[4] = {u.x, u.y, u.z, u.w};
#pragma unroll
    for (int i = 0; i < 4; ++i) {
      f16 hh = (f16)uv[i];
      sm.ts.hi[n4 + i][c] = hh;
      sm.ts.lo[n4 + i][c] = (f16)(uv[i] - (float)hh);
    }
  }
  __syncthreads();

  half8 ah[8], al[8];
#pragma unroll
  for (int kc = 0; kc < 8; ++kc) {
    ah[kc] = *reinterpret_cast<const half8*>(&sm.ts.hi[g * 16 + row16][kc * 32 + quad * 8]);
    al[kc] = *reinterpret_cast<const half8*>(&sm.ts.lo[g * 16 + row16][kc * 32 + quad * 8]);
  }
  __syncthreads();

  if (z < 2) {
    f16* outp = z ? kp : qp;
#pragma unroll
    for (int ct8 = 0; ct8 < 8; ++ct8) {
      int ct = h * 8 + ct8;
      f32x4 acc = {0.f, 0.f, 0.f, 0.f};
      const f16* bh = WT + ((size_t)ct * 8) * 512 + lane * 8;
#pragma unroll
      for (int kc = 0; kc < 8; ++kc) {
        half8 b = ldg8(bh + kc * 512);
        acc = __builtin_amdgcn_mfma_f32_16x16x32_f16(ah[kc], b, acc, 0, 0, 0);
        acc = __builtin_amdgcn_mfma_f32_16x16x32_f16(al[kc], b, acc, 0, 0, 0);
      }
      int co = ct * 16 + row16;
      float bb = bias[co];
#pragma unroll
      for (int r = 0; r < 4; ++r)
        sm.ex[g][quad * 4 + r][co] = (f16)(acc[r] + bb);
    }
    const f16* exr = &sm.ex[g][row16][0];
    size_t fb = ((size_t)bl * 64 + (n0 >> 4) + g) * 8;
#pragma unroll
    for (int k = 0; k < 4; ++k) {
      int kc = h * 4 + k;
      half8 hv = *reinterpret_cast<const half8*>(exr + kc * 32 + quad * 8);
      *reinterpret_cast<half8*>(outp + (fb + kc) * 512 + lane * 8) = hv;
    }
  } else {
#pragma unroll
    for (int ct8 = 0; ct8 < 8; ++ct8) {
      int ct = h * 8 + ct8;
      f32x4 acc = {0.f, 0.f, 0.f, 0.f};
      const f16* bh = WT + ((size_t)ct * 8) * 512 + lane * 8;
#pragma unroll
      for (int kc = 0; kc < 8; ++kc) {
        half8 b = ldg8(bh + kc * 512);
        acc = __builtin_amdgcn_mfma_f32_16x16x32_f16(ah[kc], b, acc, 0, 0, 0);
        acc = __builtin_amdgcn_mfma_f32_16x16x32_f16(al[kc], b, acc, 0, 0, 0);
      }
      int co = ct * 16 + row16;
      float bb = bias[co];
#pragma unroll
      for (int r = 0; r < 4; ++r)
        sm.exv[co][g * 16 + quad * 4 + r] = (f16)(acc[r] + bb);
    }
    __syncthreads();
    size_t vb = ((size_t)bl * 32 + blockIdx.y) * 16;
#pragma unroll
    for (int f = 0; f < 4; ++f) {
      int ct = wave * 4 + f;
      half8 o = *reinterpret_cast<const half8*>(&sm.exv[ct * 16 + row16][quad * 8]);
      *reinterpret_cast<half8*>(vp + (vb + ct) * 512 + lane * 8) = o;
    }
  }
}

// ---------------- fused flash attention + MLP + LN — LDS-shared q tiles, reg-prefetch ----------------
// grid (nb, 16). block 256 = 4 waves (16 j-rows each), all sharing a 32-i q tile staged in LDS.
// Per 32-i iteration: ds_write staged tile -> barrier -> prefetch next tile (global, overlaps)
// -> scores from LDS -> (every 4th iter) softmax over 128 i + PV (v from global) -> barrier.
// P and phase-B exchanges chunk through a per-wave [16][40] scratch (same-wave, no barrier).
struct __align__(16) AttnSmem {
  f16 qs[8192];          // 16 KB staged q tile (32 i, 16 frags of 1 KB)
  f16 scr[4][16][40];    // per-wave scratch (P / att / h exchange)  5 KB
};

__global__ void __launch_bounds__(256) k_attn_mlp(
    const f16* __restrict__ qp, const f16* __restrict__ kp, const f16* __restrict__ vp,
    const f16* __restrict__ w1p, const float* __restrict__ b1,
    const f16* __restrict__ w2p, const float* __restrict__ b2,
    const float* __restrict__ gamma, const float* __restrict__ beta,
    float* __restrict__ out, int b_base) {
  __shared__ AttnSmem sm;
  int bl = blockIdx.x, bg = b_base + bl;
  int j0 = blockIdx.y * 64;
  int tid = threadIdx.x, wave = tid >> 6, lane = tid & 63;
  int row16 = lane & 15, quad = lane >> 4;
  int jw = j0 + wave * 16;

  // A-frags: k rows j (packed)
  const f16* kbase = kp + (size_t)bl * NN * CC;
  int jt = (j0 >> 4) + wave;
  half8 kf[8];
#pragma unroll
  for (int kc = 0; kc < 8; ++kc)
    kf[kc] = ldg8(kbase + ((size_t)jt * 8 + kc) * 512 + lane * 8);

  const uint4* qsrc = reinterpret_cast<const uint4*>(qp + (size_t)bl * NN * CC);
  const f16* vbase = vp + (size_t)bl * CC * NN;
  uint4* qdst = reinterpret_cast<uint4*>(sm.qs);

  // prefetch tile 0 (each thread owns 64 B of the 16 KB tile)
  uint4 qr[4];
#pragma unroll
  for (int u = 0; u < 4; ++u) qr[u] = qsrc[tid * 4 + u];

  f32x4 O[16];
#pragma unroll
  for (int ct = 0; ct < 16; ++ct) O[ct] = {0.f, 0.f, 0.f, 0.f};
  float m_run[4], l_lane[4];
#pragma unroll
  for (int r = 0; r < 4; ++r) { m_run[r] = -1e30f; l_lane[r] = 0.f; }
  f32x4 s[8];

  for (int t = 0; t < 32; ++t) {
    // commit staged tile to LDS
#pragma unroll
    for (int u = 0; u < 4; ++u) qdst[tid * 4 + u] = qr[u];
    __syncthreads();  // tile visible to all waves
    if (t < 31) {
      // prefetch next tile; latency overlaps the compute below
#pragma unroll
      for (int u = 0; u < 4; ++u) qr[u] = qsrc[(size_t)(t + 1) * 1024 + tid * 4 + u];
    }
    int ph = t & 3;
    if (ph == 0) {
#pragma unroll
      for (int f = 0; f < 8; ++f) s[f] = {0.f, 0.f, 0.f, 0.f};
    }
    // scores for this 32-i tile (2 sub-frags) from LDS
#pragma unroll
    for (int kc = 0; kc < 8; ++kc) {
      half8 b0 = *reinterpret_cast<const half8*>(&sm.qs[(0 * 8 + kc) * 512 + lane * 8]);
      half8 b1v = *reinterpret_cast<const half8*>(&sm.qs[(1 * 8 + kc) * 512 + lane * 8]);
      s[ph * 2 + 0] = __builtin_amdgcn_mfma_f32_16x16x32_f16(kf[kc], b0, s[ph * 2 + 0], 0, 0, 0);
      s[ph * 2 + 1] = __builtin_amdgcn_mfma_f32_16x16x32_f16(kf[kc], b1v, s[ph * 2 + 1], 0, 0, 0);
    }
    if (ph == 3) {
      // softmax over 128 i (lazy l); p-values overwrite s[] in place
      float alpha[4];
#pragma unroll
      for (int r = 0; r < 4; ++r) {
        float mx = s[0][r];
#pragma unroll
        for (int f = 1; f < 8; ++f) mx = fmaxf(mx, s[f][r]);
#pragma unroll
        for (int off = 1; off < 16; off <<= 1) mx = fmaxf(mx, __shfl_xor(mx, off, 64));
        float mnew = fmaxf(m_run[r], mx);
        alpha[r] = __expf(m_run[r] - mnew);
        m_run[r] = mnew;
        float ps = 0.f;
#pragma unroll
        for (int f = 0; f < 8; ++f) {
          float pv = __expf(s[f][r] - mnew);
          s[f][r] = pv;
          ps += pv;
        }
        l_lane[r] = l_lane[r] * alpha[r] + ps;
      }
#pragma unroll
      for (int ct = 0; ct < 16; ++ct)
#pragma unroll
        for (int r = 0; r < 4; ++r) O[ct][r] *= alpha[r];

      // PV over the 4 32-i chunks; P via per-wave scratch, v from global (packed frags)
      int it128 = t >> 2;
#pragma unroll
      for (int c4 = 0; c4 < 4; ++c4) {
#pragma unroll
        for (int r = 0; r < 4; ++r) {
          sm.scr[wave][quad * 4 + r][row16]      = (f16)s[2 * c4][r];
          sm.scr[wave][quad * 4 + r][16 + row16] = (f16)s[2 * c4 + 1][r];
        }
        half8 pf = *reinterpret_cast<const half8*>(&sm.scr[wave][row16][quad * 8]);
        size_t vfb = ((size_t)(it128 * 4 + c4) * 16) * 512;
#pragma unroll
        for (int ct = 0; ct < 16; ++ct) {
          half8 vf = ldg8(vbase + vfb + (size_t)ct * 512 + lane * 8);
          O[ct] = __builtin_amdgcn_mfma_f32_16x16x32_f16(pf, vf, O[ct], 0, 0, 0);
        }
      }
    }
    __syncthreads();  // all reads of this tile done before next ds_write
  }

  // final l reduction and normalization
  float inv[4];
#pragma unroll
  for (int r = 0; r < 4; ++r) {
    float l = l_lane[r];
#pragma unroll
    for (int off = 1; off < 16; off <<= 1) l += __shfl_xor(l, off, 64);
    inv[r] = 1.f / l;
  }

  // ---- phase B: MLP + LN; exchanges chunk through per-wave scratch ----
  half8 af[8];
#pragma unroll
  for (int kc = 0; kc < 8; ++kc) {
#pragma unroll
    for (int r = 0; r < 4; ++r) {
      sm.scr[wave][quad * 4 + r][row16]      = (f16)(O[2 * kc][r] * inv[r]);
      sm.scr[wave][quad * 4 + r][16 + row16] = (f16)(O[2 * kc + 1][r] * inv[r]);
    }
    af[kc] = *reinterpret_cast<const half8*>(&sm.scr[wave][row16][quad * 8]);
  }

  // GEMM1: h = silu(att @ w1 + b1), accumulate all 16 ct
  f32x4 hacc[16];
#pragma unroll
  for (int ct = 0; ct < 16; ++ct) {
    f32x4 acc = {0.f, 0.f, 0.f, 0.f};
    const f16* brow = w1p + ((size_t)ct * 8) * 512 + lane * 8;
#pragma unroll
    for (int kc = 0; kc < 8; ++kc)
      acc = __builtin_amdgcn_mfma_f32_16x16x32_f16(af[kc], ldg8(brow + kc * 512), acc, 0, 0, 0);
    float bb = b1[ct * 16 + row16];
#pragma unroll
    for (int r = 0; r < 4; ++r) {
      float xg = acc[r] + bb;
      acc[r] = xg / (1.f + __expf(-xg));  // SiLU
    }
    hacc[ct] = acc;
  }

  // h frags via chunked exchange
  half8 hf[8];
#pragma unroll
  for (int kc = 0; kc < 8; ++kc) {
#pragma unroll
    for (int r = 0; r < 4; ++r) {
      sm.scr[wave][quad * 4 + r][row16]      = (f16)hacc[2 * kc][r];
      sm.scr[wave][quad * 4 + r][16 + row16] = (f16)hacc[2 * kc + 1][r];
    }
    hf[kc] = *reinterpret_cast<const half8*>(&sm.scr[wave][row16][quad * 8]);
  }

  f32x4 acc2[16];
#pragma unroll
  for (int ct = 0; ct < 16; ++ct) {
    f32x4 acc = {0.f, 0.f, 0.f, 0.f};
    const f16* brow = w2p + ((size_t)ct * 8) * 512 + lane * 8;
#pragma unroll
    for (int kc = 0; kc < 8; ++kc)
      acc = __builtin_amdgcn_mfma_f32_16x16x32_f16(hf[kc], ldg8(brow + kc * 512), acc, 0, 0, 0);
    float bb = b2[ct * 16 + row16];
#pragma unroll
    for (int r = 0; r < 4; ++r) acc[r] += bb;
    acc2[ct] = acc;
  }

  // LayerNorm over C (per-row stats via 16-lane butterfly)
  float sum[4] = {0.f, 0.f, 0.f, 0.f}, ssq[4] = {0.f, 0.f, 0.f, 0.f};
#pragma unroll
  for (int ct = 0; ct < 16; ++ct)
#pragma unroll
    for (int r = 0; r < 4; ++r) { float xv = acc2[ct][r]; sum[r] += xv; ssq[r] += xv * xv; }
  float mean[4], rstd[4];
#pragma unroll
  for (int r = 0; r < 4; ++r) {
#pragma unroll
    for (int off = 1; off < 16; off <<= 1) {
      sum[r] += __shfl_xor(sum[r], off, 64);
      ssq[r] += __shfl_xor(ssq[r], off, 64);
    }
    mean[r] = sum[r] * (1.f / 256.f);
    float var = ssq[r] * (1.f / 256.f) - mean[r] * mean[r];
    rstd[r] = rsqrtf(var + 1e-5f);
  }

  // direct coalesced stores: out[bg][col][jw + quad*4 .. +3] = float4
#pragma unroll
  for (int ct = 0; ct < 16; ++ct) {
    int col = ct * 16 + row16;
    float g = gamma[col], be = beta[col];
    f32x4 v;
#pragma unroll
    for (int r = 0; r < 4; ++r) v[r] = (acc2[ct][r] - mean[r]) * rstd[r] * g + be;
    *reinterpret_cast<f32x4*>(out + (size_t)(bg * CC + col) * NN + jw + quad * 4) = v;
  }
}

extern "C" void kernel_launch(void* const* d_in, const int* in_sizes, int n_in,
                              void* d_out, int out_size, void* d_ws, size_t ws_size,
                              hipStream_t stream) {
  (void)in_sizes; (void)n_in; (void)out_size;
  const float* x     = (const float*)d_in[0];
  const float* wq    = (const float*)d_in[1];
  const float* bq    = (const float*)d_in[2];
  const float* wk    = (const float*)d_in[3];
  const float* bk    = (const float*)d_in[4];
  const float* wv    = (const float*)d_in[5];
  const float* bv    = (const float*)d_in[6];
  const float* w1    = (const float*)d_in[7];
  const float* b1    = (const float*)d_in[8];
  const float* w2    = (const float*)d_in[9];
  const float* b2    = (const float*)d_in[10];
  const float* gamma = (const float*)d_in[11];
  const float* beta  = (const float*)d_in[12];
  float* out = (float*)d_out;

  const size_t WE = 65536;
  const size_t SB = (size_t)NN * CC;
  f16* base = (f16*)d_ws;
  f16* wqp = base + 0 * WE;
  f16* wkp = base + 1 * WE;
  f16* wvp = base + 2 * WE;
  f16* w1p = base + 3 * WE;
  f16* w2p = base + 4 * WE;

  size_t wbytes = 5 * WE * sizeof(f16);
  size_t perb   = 3 * SB * sizeof(f16);
  int nb = (ws_size > wbytes) ? (int)((ws_size - wbytes) / perb) : 1;
  if (nb < 1) nb = 1;
  if (nb > BB) nb = BB;

  f16* qb  = base + 5 * WE;
  f16* kb  = qb + (size_t)nb * SB;
  f16* vTb = kb + (size_t)nb * SB;

  WP5 p;
  p.s[0] = wq; p.s[1] = wk; p.s[2] = wv; p.s[3] = w1; p.s[4] = w2;
  p.d[0] = wqp; p.d[1] = wkp; p.d[2] = wvp; p.d[3] = w1p; p.d[4] = w2p;
  k_packW<<<dim3(16, 5), 256, 0, stream>>>(p);

  for (int b0 = 0; b0 < BB; b0 += nb) {
    int cb = (b0 + nb <= BB) ? nb : (BB - b0);
    k_qkv<<<dim3(cb, 32, 3), 256, 0, stream>>>(x, wqp, wkp, wvp, bq, bk, bv, qb, kb, vTb, b0);
    k_attn_mlp<<<dim3(cb, 16), 256, 0, stream>>>(qb, kb, vTb, w1p, b1, w2p, b2,
                                                 gamma, beta, out, b0);
  }
}